// Round 16
// baseline (194.221 us; speedup 1.0000x reference)
//
#include <hip/hip_runtime.h>
#include <math.h>

// Problem constants (from reference)
#define BB   8      // batch
#define MM   4      // MAXM
#define DD   128    // DIM
#define NHH  8      // heads
#define QDD  16     // head dim
#define NN   256    // H*W
#define KO   128    // NH*QD
#define ATILE 16    // i-rows per a_kernel block
#define DTILE 8     // D-rows per out_kernel block

// ---------------------------------------------------------------------------
// Kernel 0 (trig-free): pe[m,i,j] = exp(i*m*theta) = ((dx+i*dy)/r)^m.
// ---------------------------------------------------------------------------
__global__ void pe_kernel(float2* __restrict__ peIJ, float2* __restrict__ peT) {
    int bid = blockIdx.x;           // m*N + i
    int m = bid >> 8;
    int i = bid & 255;
    int j = threadIdx.x;
    float dy = (float)((j >> 4) - (i >> 4));
    float dx = (float)((j & 15) - (i & 15));
    float r2 = dx * dx + dy * dy;
    float c1 = 1.f, s1 = 0.f;
    if (r2 > 0.f) {
        float rinv = rsqrtf(r2);
        c1 = dx * rinv; s1 = dy * rinv;
    }
    float c = 1.f, s = 0.f;
    for (int k = 0; k < m; ++k) {   // m is block-uniform (0..3)
        float nc = c * c1 - s * s1;
        s = c * s1 + s * c1;
        c = nc;
    }
    peIJ[(m * NN + i) * NN + j] = make_float2(c, s);
    peT[(m * NN + j) * NN + i] = make_float2(c, s);
}

// ---------------------------------------------------------------------------
// Kernel 1 (v7): E[t,b,m,h,q,n] = sum_D emb[t,m,h,q,D]*x[b,m,D,n]
// v6 + D-chunked register batching: per chunk of 4 D, ALL 16 emb values and
// 8 x-float4s are loaded into registers up front (deep outstanding queue,
// LDS throughput regime ~5.8cyc/read), then 256 FMA run with no LDS waits.
// v6 read 4 emb per D and consumed immediately -> ~120cyc LDS latency per
// iteration = the pinned 52% VALUBusy.
// ---------------------------------------------------------------------------
__global__ __launch_bounds__(256, 3)
void e_kernel(const float* __restrict__ xr, const float* __restrict__ xi,
              const float* __restrict__ er, const float* __restrict__ ei,
              float2* __restrict__ E) {
    int bid = blockIdx.x;
    int h = bid & 7;  bid >>= 3;
    int m = bid & 3;  bid >>= 2;
    int b = bid & 7;  bid >>= 3;
    int t = bid;                          // 0..2
    int tid = threadIdx.x;
    int wav = tid >> 6;                   // 0..3 (wave id = q-quad)
    int lane = tid & 63;                  // n = 4*lane .. 4*lane+3

    __shared__ float2 semb[QDD * DD];     // 16 KB, [q*128+D] (linear)
    int base = (((t * MM + m) * NHH + h) * QDD) * DD;
    for (int idx = tid; idx < QDD * DD; idx += 256)
        semb[idx] = make_float2(er[base + idx], ei[base + idx]);
    __syncthreads();

    float accr[4][4], acci[4][4];
#pragma unroll
    for (int q = 0; q < 4; ++q)
#pragma unroll
        for (int c = 0; c < 4; ++c) { accr[q][c] = 0.f; acci[q][c] = 0.f; }

    const float4* xr4 = (const float4*)(xr + (size_t)((b * MM + m) * DD) * NN);
    const float4* xi4 = (const float4*)(xi + (size_t)((b * MM + m) * DD) * NN);
    const float2* sq = semb + wav * 4 * DD;   // this wave's 4 q rows

    for (int Dc = 0; Dc < DD; Dc += 4) {
        // batch-load emb chunk: 16 float2 (statically indexed -> registers)
        float2 em[4][4];
#pragma unroll
        for (int qq = 0; qq < 4; ++qq)
#pragma unroll
            for (int d = 0; d < 4; ++d)
                em[qq][d] = sq[qq * DD + Dc + d];
        // batch-load x chunk: 8 float4
        float4 vr[4], vi[4];
#pragma unroll
        for (int d = 0; d < 4; ++d) {
            vr[d] = xr4[(Dc + d) * 64 + lane];
            vi[d] = xi4[(Dc + d) * 64 + lane];
        }
        // 256 FMA with no memory waits inside
#pragma unroll
        for (int d = 0; d < 4; ++d) {
#pragma unroll
            for (int qq = 0; qq < 4; ++qq) {
                float2 e = em[qq][d];
                accr[qq][0] = fmaf(e.x, vr[d].x, fmaf(-e.y, vi[d].x, accr[qq][0]));
                acci[qq][0] = fmaf(e.x, vi[d].x, fmaf( e.y, vr[d].x, acci[qq][0]));
                accr[qq][1] = fmaf(e.x, vr[d].y, fmaf(-e.y, vi[d].y, accr[qq][1]));
                acci[qq][1] = fmaf(e.x, vi[d].y, fmaf( e.y, vr[d].y, acci[qq][1]));
                accr[qq][2] = fmaf(e.x, vr[d].z, fmaf(-e.y, vi[d].z, accr[qq][2]));
                acci[qq][2] = fmaf(e.x, vi[d].z, fmaf( e.y, vr[d].z, acci[qq][2]));
                accr[qq][3] = fmaf(e.x, vr[d].w, fmaf(-e.y, vi[d].w, accr[qq][3]));
                acci[qq][3] = fmaf(e.x, vi[d].w, fmaf( e.y, vr[d].w, acci[qq][3]));
            }
        }
    }

    size_t ebase = (size_t)((((t * BB + b) * MM + m) * NHH + h) * QDD + wav * 4) * NN
                 + 4 * lane;
#pragma unroll
    for (int qq = 0; qq < 4; ++qq) {
        float4* E4 = (float4*)(E + ebase + (size_t)qq * NN);
        E4[0] = make_float4(accr[qq][0], acci[qq][0], accr[qq][1], acci[qq][1]);
        E4[1] = make_float4(accr[qq][2], acci[qq][2], accr[qq][3], acci[qq][3]);
    }
}

// ---------------------------------------------------------------------------
// Kernel 2: QE[b,m,h,i] = sum_q conj(E0[b,m,h,q,i]) * enc0[m,h,q]
// ---------------------------------------------------------------------------
__global__ void qe_kernel(const float2* __restrict__ E,
                          const float* __restrict__ encr, const float* __restrict__ enci,
                          float2* __restrict__ QE) {
    int bid = blockIdx.x;                 // (b*MM+m)*NHH + h
    int i = threadIdx.x;
    const float2* e0 = E + (size_t)(bid) * QDD * NN;   // t=0 plane
    int h = bid & 7;
    int bm = bid >> 3;
    int m = bm & 3;
    int encbase = (m * NHH + h) * QDD;    // enc[0,m,h,0,q,0]
    float ar = 0.f, ai = 0.f;
#pragma unroll
    for (int q = 0; q < QDD; ++q) {
        float2 e = e0[q * NN + i];
        float cr = encr[encbase + q], ci = enci[encbase + q];
        // conj(e) * enc
        ar = fmaf(e.x, cr, fmaf( e.y, ci, ar));
        ai = fmaf(e.x, ci, fmaf(-e.y, cr, ai));
    }
    QE[(size_t)bid * NN + i] = make_float2(ar, ai);
}

// ---------------------------------------------------------------------------
// Kernel 3 (register-tiled, UNFUSED): A[b,h,i,j] =
//   sum_m [ sum_q conj(E0[b,m,h,q,i])*K[b,m,h,q,j] + QE[b,m,h,i]*pe[m,i,j] ]
// ---------------------------------------------------------------------------
__global__ void a_kernel(const float2* __restrict__ E, const float2* __restrict__ QE,
                         const float2* __restrict__ peIJ, float2* __restrict__ A) {
    int bid = blockIdx.x;                 // (b*NHH+h)*16 + itile
    int itile = bid & 15;
    int bh = bid >> 4;
    int h = bh & 7;
    int b = bh >> 3;
    int j = threadIdx.x;
    int i0 = itile * ATILE;

    __shared__ float2 sk[QDD][NN];        // 32 KB
    __shared__ float2 se[ATILE][QDD];     // 2 KB
    __shared__ float2 sqe[ATILE];

    float ar[ATILE], ai[ATILE];
#pragma unroll
    for (int r = 0; r < ATILE; ++r) { ar[r] = 0.f; ai[r] = 0.f; }

    for (int m = 0; m < MM; ++m) {
        const float2* kk = E + (size_t)((((BB + b) * MM + m) * NHH + h) * QDD) * NN; // t=1
        const float2* e0 = E + (size_t)(((b * MM + m) * NHH + h) * QDD) * NN;        // t=0
        __syncthreads();
        for (int idx = threadIdx.x; idx < QDD * NN; idx += 256)
            sk[idx >> 8][idx & 255] = kk[idx];
        {
            int q = threadIdx.x & 15;
            int r = threadIdx.x >> 4;     // 0..15
            se[r][q] = e0[q * NN + i0 + r];
        }
        if (threadIdx.x < ATILE)
            sqe[threadIdx.x] = QE[(size_t)((b * MM + m) * NHH + h) * NN + i0 + threadIdx.x];
        __syncthreads();

        // this thread's K column into registers
        float2 kreg[QDD];
#pragma unroll
        for (int q = 0; q < QDD; ++q) kreg[q] = sk[q][j];

#pragma unroll
        for (int r = 0; r < ATILE; ++r) {
#pragma unroll
            for (int q = 0; q < QDD; ++q) {
                float2 e = se[r][q];      // block-uniform broadcast
                ar[r] = fmaf(e.x, kreg[q].x, fmaf( e.y, kreg[q].y, ar[r]));
                ai[r] = fmaf(e.x, kreg[q].y, fmaf(-e.y, kreg[q].x, ai[r]));
            }
            float2 p  = peIJ[(size_t)(m * NN + i0 + r) * NN + j];   // coalesced
            float2 qe = sqe[r];
            ar[r] = fmaf(qe.x, p.x, fmaf(-qe.y, p.y, ar[r]));
            ai[r] = fmaf(qe.x, p.y, fmaf( qe.y, p.x, ai[r]));
        }
    }
#pragma unroll
    for (int r = 0; r < ATILE; ++r)
        A[(size_t)(bh * NN + i0 + r) * NN + j] = make_float2(ar[r], ai[r]);
}

// ---------------------------------------------------------------------------
// Kernel 4: row softmax of |A|/4 over j; writes TRANSPOSED Aw:
//   AwT[(bh*N + j)*N + i]
// ---------------------------------------------------------------------------
__global__ void softmax_kernel(const float2* __restrict__ A, float* __restrict__ AwT) {
    int row = blockIdx.x;                 // (b*NHH+h)*NN + i
    int j = threadIdx.x;
    float2 a = A[(size_t)row * NN + j];
    float v = sqrtf(fmaf(a.x, a.x, a.y * a.y)) * 0.25f;

    __shared__ float smax[4];
    __shared__ float ssum[4];
    int lane = threadIdx.x & 63;
    int wid  = threadIdx.x >> 6;

    float mv = v;
#pragma unroll
    for (int off = 32; off > 0; off >>= 1) mv = fmaxf(mv, __shfl_xor(mv, off));
    if (lane == 0) smax[wid] = mv;
    __syncthreads();
    float mx = fmaxf(fmaxf(smax[0], smax[1]), fmaxf(smax[2], smax[3]));

    float e = expf(v - mx);
    float sv = e;
#pragma unroll
    for (int off = 32; off > 0; off >>= 1) sv += __shfl_xor(sv, off);
    if (lane == 0) ssum[wid] = sv;
    __syncthreads();
    float sum = ssum[0] + ssum[1] + ssum[2] + ssum[3];

    float aw = e / sum;
    int bh = row >> 8;
    int i  = row & 255;
    AwT[(size_t)(bh * NN + j) * NN + i] = aw;
}

// ---------------------------------------------------------------------------
// Kernel 5 (qh-split): block = (b,m,h,qh of 8 q), 512 thr = 2 jg x 256 i.
// ---------------------------------------------------------------------------
__global__ __launch_bounds__(512)
void res_kernel(const float2* __restrict__ E, const float* __restrict__ AwT,
                const float2* __restrict__ peT,
                const float* __restrict__ encr, const float* __restrict__ enci,
                float2* __restrict__ Res) {
    int bid = blockIdx.x;                 // ((b*MM+m)*NHH+h)*2 + qh
    int qh = bid & 1; bid >>= 1;
    int h = bid & 7;
    int bm = bid >> 3;
    int m = bm & 3;
    int b = bm >> 2;
    int i = threadIdx.x & 255;
    int g = threadIdx.x >> 8;             // j-half 0/1

    __shared__ float2 sv[8][NN];          // 16 KB: this qh's 8 V rows
    __shared__ float2 spA[NN][9];         // 18 KB: g=1 partials (8 acc + PA)
    __shared__ float2 senc[8];

    const float2* V = E + ((size_t)(((2 * BB + b) * MM + m) * NHH + h) * QDD + qh * 8) * NN;
    for (int idx = threadIdx.x; idx < 8 * NN; idx += 512) sv[idx >> 8][idx & 255] = V[idx];
    if (threadIdx.x < 8) {
        int eb = ((MM + m) * NHH + h) * QDD + qh * 8 + threadIdx.x;   // enc[1,...]
        senc[threadIdx.x] = make_float2(encr[eb], enci[eb]);
    }
    __syncthreads();

    float accr[8], acci[8];
#pragma unroll
    for (int q = 0; q < 8; ++q) { accr[q] = 0.f; acci[q] = 0.f; }
    float par = 0.f, pai = 0.f;

    const float*  awp = AwT + (size_t)((b * NHH + h) * NN) * NN + i;
    const float2* pep = peT + (size_t)(m * NN) * NN + i;
    int j0 = g * (NN / 2);
    for (int j = j0; j < j0 + NN / 2; ++j) {
        float aw  = awp[(size_t)j * NN];      // coalesced over i
        float2 p  = pep[(size_t)j * NN];      // coalesced over i
        par = fmaf(p.x, aw, par);
        pai = fmaf(p.y, aw, pai);
#pragma unroll
        for (int q = 0; q < 8; ++q) {
            float2 vv = sv[q][j];             // wave-uniform -> broadcast
            accr[q] = fmaf(vv.x, aw, accr[q]);
            acci[q] = fmaf(vv.y, aw, acci[q]);
        }
    }

    if (g == 1) {
#pragma unroll
        for (int q = 0; q < 8; ++q) spA[i][q] = make_float2(accr[q], acci[q]);
        spA[i][8] = make_float2(par, pai);
    }
    __syncthreads();
    if (g == 0) {
#pragma unroll
        for (int q = 0; q < 8; ++q) {
            float2 o = spA[i][q];
            accr[q] += o.x; acci[q] += o.y;
        }
        float2 o = spA[i][8];
        par += o.x; pai += o.y;

        float2* rp = Res + ((size_t)((b * MM + m) * KO + h * QDD + qh * 8)) * NN + i;
#pragma unroll
        for (int q = 0; q < 8; ++q) {
            float2 e1 = senc[q];
            float rr = accr[q] + e1.x * par - e1.y * pai;
            float ri = acci[q] + e1.x * pai + e1.y * par;
            rp[(size_t)q * NN] = make_float2(rr, ri);
        }
    }
}

// ---------------------------------------------------------------------------
// Kernel 6 (DTILE=8): out[b,m,D,n] = sum_k w_out[m,D,k]*res[b,m,k,n].
// ---------------------------------------------------------------------------
__global__ void out_kernel(const float2* __restrict__ Res,
                           const float* __restrict__ wor, const float* __restrict__ woi,
                           float* __restrict__ out) {
    int bid = blockIdx.x;                 // (b*MM+m)*(DD/DTILE) + dtile
    int dt = bid & (DD / DTILE - 1);
    int bm = bid >> 4;                    // DD/DTILE == 16
    int n = threadIdx.x;
    int D0 = dt * DTILE;
    int m = bm & 3;

    __shared__ float2 sw[DTILE][KO];      // 8 KB
    for (int idx = threadIdx.x; idx < DTILE * KO; idx += 256) {
        int d = idx >> 7, k = idx & 127;
        int wb = (m * DD + D0 + d) * KO + k;
        sw[d][k] = make_float2(wor[wb], woi[wb]);
    }
    __syncthreads();

    const float2* rp = Res + (size_t)(bm * KO) * NN + n;
    float ar[DTILE], ai[DTILE];
#pragma unroll
    for (int d = 0; d < DTILE; ++d) { ar[d] = 0.f; ai[d] = 0.f; }

    for (int k = 0; k < KO; ++k) {
        float2 r = rp[(size_t)k * NN];    // coalesced
#pragma unroll
        for (int d = 0; d < DTILE; ++d) {
            float2 w = sw[d][k];          // broadcast
            ar[d] = fmaf(w.x, r.x, fmaf(-w.y, r.y, ar[d]));
            ai[d] = fmaf(w.x, r.y, fmaf( w.y, r.x, ai[d]));
        }
    }
#pragma unroll
    for (int d = 0; d < DTILE; ++d) {
        size_t ob = (size_t)(bm * DD + D0 + d) * NN + n;
        out[ob] = ar[d];
        out[(size_t)BB * MM * DD * NN + ob] = ai[d];
    }
}

// ---------------------------------------------------------------------------
extern "C" void kernel_launch(void* const* d_in, const int* in_sizes, int n_in,
                              void* d_out, int out_size, void* d_ws, size_t ws_size,
                              hipStream_t stream) {
    (void)in_sizes; (void)n_in; (void)out_size; (void)ws_size;

    const float* x_re   = (const float*)d_in[0];
    const float* x_im   = (const float*)d_in[1];
    const float* emb_re = (const float*)d_in[2];
    const float* emb_im = (const float*)d_in[3];
    const float* enc_re = (const float*)d_in[4];
    const float* enc_im = (const float*)d_in[5];
    const float* out_re = (const float*)d_in[6];
    const float* out_im = (const float*)d_in[7];
    float* out = (float*)d_out;

    // Workspace layout (floats). Total ~155.7 MB.
    float* ws = (float*)d_ws;
    size_t off = 0;
    float2* peIJ = (float2*)(ws + off); off += (size_t)MM * NN * NN * 2;          // 524288
    float2* peT  = (float2*)(ws + off); off += (size_t)MM * NN * NN * 2;          // 524288
    float2* E    = (float2*)(ws + off); off += (size_t)3 * BB * MM * NHH * QDD * NN * 2; // 25165824
    float2* QE   = (float2*)(ws + off); off += (size_t)BB * MM * NHH * NN * 2;    // 131072
    float2* A    = (float2*)(ws + off); off += (size_t)BB * NHH * NN * NN * 2;    // 8388608
    float*  AwT  = (float*)(ws + off);  off += (size_t)BB * NHH * NN * NN;        // 4194304
    float2* Res  = A;  // alias: A is dead after softmax; Res needs 2097152 floats

    pe_kernel<<<MM * NN, 256, 0, stream>>>(peIJ, peT);
    e_kernel<<<3 * BB * MM * NHH, 256, 0, stream>>>(x_re, x_im, emb_re, emb_im, E);
    qe_kernel<<<BB * MM * NHH, 256, 0, stream>>>(E, enc_re, enc_im, QE);
    a_kernel<<<BB * NHH * ATILE, 256, 0, stream>>>(E, QE, peIJ, A);
    softmax_kernel<<<BB * NHH * NN, 256, 0, stream>>>(A, AwT);
    res_kernel<<<BB * MM * NHH * 2, 512, 0, stream>>>(E, AwT, peT, enc_re, enc_im, Res);
    out_kernel<<<BB * MM * (DD / DTILE), 256, 0, stream>>>(Res, out_re, out_im, out);
}

// Round 17
// 184.837 us; speedup vs baseline: 1.0508x; 1.0508x over previous
//
#include <hip/hip_runtime.h>
#include <math.h>

// Problem constants (from reference)
#define BB   8      // batch
#define MM   4      // MAXM
#define DD   128    // DIM
#define NHH  8      // heads
#define QDD  16     // head dim
#define NN   256    // H*W
#define KO   128    // NH*QD
#define ATILE 16    // i-rows per a_kernel block
#define DTILE 8     // D-rows per out_kernel block

// XCD swizzle note [T1]: MI355X dispatches consecutive blockIdx round-robin
// over 8 XCDs (bid%8 = XCD heuristic). Each kernel below decodes blockIdx so
// that all blocks sharing a data panel have the same bid%8 -> panel lives in
// ONE XCD's 4MB L2 instead of being re-fetched from HBM by all 8.

// ---------------------------------------------------------------------------
// Kernel 0 (trig-free): pe[m,i,j] = exp(i*m*theta) = ((dx+i*dy)/r)^m.
// ---------------------------------------------------------------------------
__global__ void pe_kernel(float2* __restrict__ peIJ, float2* __restrict__ peT) {
    int bid = blockIdx.x;           // m*N + i
    int m = bid >> 8;
    int i = bid & 255;
    int j = threadIdx.x;
    float dy = (float)((j >> 4) - (i >> 4));
    float dx = (float)((j & 15) - (i & 15));
    float r2 = dx * dx + dy * dy;
    float c1 = 1.f, s1 = 0.f;
    if (r2 > 0.f) {
        float rinv = rsqrtf(r2);
        c1 = dx * rinv; s1 = dy * rinv;
    }
    float c = 1.f, s = 0.f;
    for (int k = 0; k < m; ++k) {   // m is block-uniform (0..3)
        float nc = c * c1 - s * s1;
        s = c * s1 + s * c1;
        c = nc;
    }
    peIJ[(m * NN + i) * NN + j] = make_float2(c, s);
    peT[(m * NN + j) * NN + i] = make_float2(c, s);
}

// ---------------------------------------------------------------------------
// Kernel 1 (v8 = v7 + XCD swizzle): E[t,b,m,h,q,n] = sum_D emb*x.
// 768 blocks = 96 idx x 8 xcd. (b,m) <- (xcd, idx&3): all 24 blocks (t,h)
// sharing one 512KB x-slice land on ONE XCD; 4 slices = 2MB <= 4MB L2.
// ---------------------------------------------------------------------------
__global__ __launch_bounds__(256, 3)
void e_kernel(const float* __restrict__ xr, const float* __restrict__ xi,
              const float* __restrict__ er, const float* __restrict__ ei,
              float2* __restrict__ E) {
    int bid = blockIdx.x;
    int xcd = bid & 7;
    int idx = bid >> 3;                   // 0..95
    int pair = xcd * 4 + (idx & 3);       // b*MM+m, 0..31
    int th  = idx >> 2;                   // 0..23 = t*NHH+h
    int t = th >> 3;
    int h = th & 7;
    int b = pair >> 2;
    int m = pair & 3;
    int tid = threadIdx.x;
    int wav = tid >> 6;                   // 0..3 (wave id = q-quad)
    int lane = tid & 63;                  // n = 4*lane .. 4*lane+3

    __shared__ float2 semb[QDD * DD];     // 16 KB, [q*128+D] (linear)
    int base = (((t * MM + m) * NHH + h) * QDD) * DD;
    for (int i2 = tid; i2 < QDD * DD; i2 += 256)
        semb[i2] = make_float2(er[base + i2], ei[base + i2]);
    __syncthreads();

    float accr[4][4], acci[4][4];
#pragma unroll
    for (int q = 0; q < 4; ++q)
#pragma unroll
        for (int c = 0; c < 4; ++c) { accr[q][c] = 0.f; acci[q][c] = 0.f; }

    const float4* xr4 = (const float4*)(xr + (size_t)((b * MM + m) * DD) * NN);
    const float4* xi4 = (const float4*)(xi + (size_t)((b * MM + m) * DD) * NN);
    const float2* sq = semb + wav * 4 * DD;   // this wave's 4 q rows

    for (int Dc = 0; Dc < DD; Dc += 4) {
        float2 em[4][4];
#pragma unroll
        for (int qq = 0; qq < 4; ++qq)
#pragma unroll
            for (int d = 0; d < 4; ++d)
                em[qq][d] = sq[qq * DD + Dc + d];
        float4 vr[4], vi[4];
#pragma unroll
        for (int d = 0; d < 4; ++d) {
            vr[d] = xr4[(Dc + d) * 64 + lane];
            vi[d] = xi4[(Dc + d) * 64 + lane];
        }
#pragma unroll
        for (int d = 0; d < 4; ++d) {
#pragma unroll
            for (int qq = 0; qq < 4; ++qq) {
                float2 e = em[qq][d];
                accr[qq][0] = fmaf(e.x, vr[d].x, fmaf(-e.y, vi[d].x, accr[qq][0]));
                acci[qq][0] = fmaf(e.x, vi[d].x, fmaf( e.y, vr[d].x, acci[qq][0]));
                accr[qq][1] = fmaf(e.x, vr[d].y, fmaf(-e.y, vi[d].y, accr[qq][1]));
                acci[qq][1] = fmaf(e.x, vi[d].y, fmaf( e.y, vr[d].y, acci[qq][1]));
                accr[qq][2] = fmaf(e.x, vr[d].z, fmaf(-e.y, vi[d].z, accr[qq][2]));
                acci[qq][2] = fmaf(e.x, vi[d].z, fmaf( e.y, vr[d].z, acci[qq][2]));
                accr[qq][3] = fmaf(e.x, vr[d].w, fmaf(-e.y, vi[d].w, accr[qq][3]));
                acci[qq][3] = fmaf(e.x, vi[d].w, fmaf( e.y, vr[d].w, acci[qq][3]));
            }
        }
    }

    size_t ebase = (size_t)((((t * BB + b) * MM + m) * NHH + h) * QDD + wav * 4) * NN
                 + 4 * lane;
#pragma unroll
    for (int qq = 0; qq < 4; ++qq) {
        float4* E4 = (float4*)(E + ebase + (size_t)qq * NN);
        E4[0] = make_float4(accr[qq][0], acci[qq][0], accr[qq][1], acci[qq][1]);
        E4[1] = make_float4(accr[qq][2], acci[qq][2], accr[qq][3], acci[qq][3]);
    }
}

// ---------------------------------------------------------------------------
// Kernel 2: QE[b,m,h,i] = sum_q conj(E0[b,m,h,q,i]) * enc0[m,h,q]
// ---------------------------------------------------------------------------
__global__ void qe_kernel(const float2* __restrict__ E,
                          const float* __restrict__ encr, const float* __restrict__ enci,
                          float2* __restrict__ QE) {
    int bid = blockIdx.x;                 // (b*MM+m)*NHH + h
    int i = threadIdx.x;
    const float2* e0 = E + (size_t)(bid) * QDD * NN;   // t=0 plane
    int h = bid & 7;
    int bm = bid >> 3;
    int m = bm & 3;
    int encbase = (m * NHH + h) * QDD;    // enc[0,m,h,0,q,0]
    float ar = 0.f, ai = 0.f;
#pragma unroll
    for (int q = 0; q < QDD; ++q) {
        float2 e = e0[q * NN + i];
        float cr = encr[encbase + q], ci = enci[encbase + q];
        // conj(e) * enc
        ar = fmaf(e.x, cr, fmaf( e.y, ci, ar));
        ai = fmaf(e.x, ci, fmaf(-e.y, cr, ai));
    }
    QE[(size_t)bid * NN + i] = make_float2(ar, ai);
}

// ---------------------------------------------------------------------------
// Kernel 3 (register-tiled + XCD swizzle): A[b,h,i,j] =
//   sum_m [ sum_q conj(E0[b,m,h,q,i])*K[b,m,h,q,j] + QE[b,m,h,i]*pe[m,i,j] ]
// 1024 blocks = 128 idx x 8 xcd. (b,h) <- (xcd, idx&7): all 16 itiles
// sharing one (b,h) K/E0 panel (~160KB) land on ONE XCD.
// ---------------------------------------------------------------------------
__global__ void a_kernel(const float2* __restrict__ E, const float2* __restrict__ QE,
                         const float2* __restrict__ peIJ, float2* __restrict__ A) {
    int bid = blockIdx.x;
    int xcd = bid & 7;
    int idx = bid >> 3;                   // 0..127
    int bh = xcd * 8 + (idx & 7);         // b*NHH+h, 0..63
    int itile = idx >> 3;                 // 0..15
    int h = bh & 7;
    int b = bh >> 3;
    int j = threadIdx.x;
    int i0 = itile * ATILE;

    __shared__ float2 sk[QDD][NN];        // 32 KB
    __shared__ float2 se[ATILE][QDD];     // 2 KB
    __shared__ float2 sqe[ATILE];

    float ar[ATILE], ai[ATILE];
#pragma unroll
    for (int r = 0; r < ATILE; ++r) { ar[r] = 0.f; ai[r] = 0.f; }

    for (int m = 0; m < MM; ++m) {
        const float2* kk = E + (size_t)((((BB + b) * MM + m) * NHH + h) * QDD) * NN; // t=1
        const float2* e0 = E + (size_t)(((b * MM + m) * NHH + h) * QDD) * NN;        // t=0
        __syncthreads();
        for (int i2 = threadIdx.x; i2 < QDD * NN; i2 += 256)
            sk[i2 >> 8][i2 & 255] = kk[i2];
        {
            int q = threadIdx.x & 15;
            int r = threadIdx.x >> 4;     // 0..15
            se[r][q] = e0[q * NN + i0 + r];
        }
        if (threadIdx.x < ATILE)
            sqe[threadIdx.x] = QE[(size_t)((b * MM + m) * NHH + h) * NN + i0 + threadIdx.x];
        __syncthreads();

        // this thread's K column into registers
        float2 kreg[QDD];
#pragma unroll
        for (int q = 0; q < QDD; ++q) kreg[q] = sk[q][j];

#pragma unroll
        for (int r = 0; r < ATILE; ++r) {
#pragma unroll
            for (int q = 0; q < QDD; ++q) {
                float2 e = se[r][q];      // block-uniform broadcast
                ar[r] = fmaf(e.x, kreg[q].x, fmaf( e.y, kreg[q].y, ar[r]));
                ai[r] = fmaf(e.x, kreg[q].y, fmaf(-e.y, kreg[q].x, ai[r]));
            }
            float2 p  = peIJ[(size_t)(m * NN + i0 + r) * NN + j];   // coalesced
            float2 qe = sqe[r];
            ar[r] = fmaf(qe.x, p.x, fmaf(-qe.y, p.y, ar[r]));
            ai[r] = fmaf(qe.x, p.y, fmaf( qe.y, p.x, ai[r]));
        }
    }
#pragma unroll
    for (int r = 0; r < ATILE; ++r)
        A[(size_t)(bh * NN + i0 + r) * NN + j] = make_float2(ar[r], ai[r]);
}

// ---------------------------------------------------------------------------
// Kernel 4: row softmax of |A|/4 over j; writes TRANSPOSED Aw:
//   AwT[(bh*N + j)*N + i]
// ---------------------------------------------------------------------------
__global__ void softmax_kernel(const float2* __restrict__ A, float* __restrict__ AwT) {
    int row = blockIdx.x;                 // (b*NHH+h)*NN + i
    int j = threadIdx.x;
    float2 a = A[(size_t)row * NN + j];
    float v = sqrtf(fmaf(a.x, a.x, a.y * a.y)) * 0.25f;

    __shared__ float smax[4];
    __shared__ float ssum[4];
    int lane = threadIdx.x & 63;
    int wid  = threadIdx.x >> 6;

    float mv = v;
#pragma unroll
    for (int off = 32; off > 0; off >>= 1) mv = fmaxf(mv, __shfl_xor(mv, off));
    if (lane == 0) smax[wid] = mv;
    __syncthreads();
    float mx = fmaxf(fmaxf(smax[0], smax[1]), fmaxf(smax[2], smax[3]));

    float e = expf(v - mx);
    float sv = e;
#pragma unroll
    for (int off = 32; off > 0; off >>= 1) sv += __shfl_xor(sv, off);
    if (lane == 0) ssum[wid] = sv;
    __syncthreads();
    float sum = ssum[0] + ssum[1] + ssum[2] + ssum[3];

    float aw = e / sum;
    int bh = row >> 8;
    int i  = row & 255;
    AwT[(size_t)(bh * NN + j) * NN + i] = aw;
}

// ---------------------------------------------------------------------------
// Kernel 5 (qh-split + XCD swizzle): 512 blocks = 64 idx x 8 xcd.
// (b,h) <- (xcd, idx&7): all 8 blocks (m,qh) sharing one 256KB AwT panel
// land on ONE XCD (8 panels = 2MB <= 4MB L2).
// ---------------------------------------------------------------------------
__global__ __launch_bounds__(512)
void res_kernel(const float2* __restrict__ E, const float* __restrict__ AwT,
                const float2* __restrict__ peT,
                const float* __restrict__ encr, const float* __restrict__ enci,
                float2* __restrict__ Res) {
    int bid = blockIdx.x;
    int xcd = bid & 7;
    int idx = bid >> 3;                   // 0..63
    int bh = xcd * 8 + (idx & 7);         // b*NHH+h
    int mqh = idx >> 3;                   // 0..7
    int m  = mqh >> 1;
    int qh = mqh & 1;
    int h = bh & 7;
    int b = bh >> 3;
    int i = threadIdx.x & 255;
    int g = threadIdx.x >> 8;             // j-half 0/1

    __shared__ float2 sv[8][NN];          // 16 KB: this qh's 8 V rows
    __shared__ float2 spA[NN][9];         // 18 KB: g=1 partials (8 acc + PA)
    __shared__ float2 senc[8];

    const float2* V = E + ((size_t)(((2 * BB + b) * MM + m) * NHH + h) * QDD + qh * 8) * NN;
    for (int i2 = threadIdx.x; i2 < 8 * NN; i2 += 512) sv[i2 >> 8][i2 & 255] = V[i2];
    if (threadIdx.x < 8) {
        int eb = ((MM + m) * NHH + h) * QDD + qh * 8 + threadIdx.x;   // enc[1,...]
        senc[threadIdx.x] = make_float2(encr[eb], enci[eb]);
    }
    __syncthreads();

    float accr[8], acci[8];
#pragma unroll
    for (int q = 0; q < 8; ++q) { accr[q] = 0.f; acci[q] = 0.f; }
    float par = 0.f, pai = 0.f;

    const float*  awp = AwT + (size_t)((b * NHH + h) * NN) * NN + i;
    const float2* pep = peT + (size_t)(m * NN) * NN + i;
    int j0 = g * (NN / 2);
    for (int j = j0; j < j0 + NN / 2; ++j) {
        float aw  = awp[(size_t)j * NN];      // coalesced over i
        float2 p  = pep[(size_t)j * NN];      // coalesced over i
        par = fmaf(p.x, aw, par);
        pai = fmaf(p.y, aw, pai);
#pragma unroll
        for (int q = 0; q < 8; ++q) {
            float2 vv = sv[q][j];             // wave-uniform -> broadcast
            accr[q] = fmaf(vv.x, aw, accr[q]);
            acci[q] = fmaf(vv.y, aw, acci[q]);
        }
    }

    if (g == 1) {
#pragma unroll
        for (int q = 0; q < 8; ++q) spA[i][q] = make_float2(accr[q], acci[q]);
        spA[i][8] = make_float2(par, pai);
    }
    __syncthreads();
    if (g == 0) {
#pragma unroll
        for (int q = 0; q < 8; ++q) {
            float2 o = spA[i][q];
            accr[q] += o.x; acci[q] += o.y;
        }
        float2 o = spA[i][8];
        par += o.x; pai += o.y;

        float2* rp = Res + ((size_t)((b * MM + m) * KO + h * QDD + qh * 8)) * NN + i;
#pragma unroll
        for (int q = 0; q < 8; ++q) {
            float2 e1 = senc[q];
            float rr = accr[q] + e1.x * par - e1.y * pai;
            float ri = acci[q] + e1.x * pai + e1.y * par;
            rp[(size_t)q * NN] = make_float2(rr, ri);
        }
    }
}

// ---------------------------------------------------------------------------
// Kernel 6 (DTILE=8 + XCD swizzle): 512 blocks = 64 idx x 8 xcd.
// (b,m) <- (xcd, idx&3): all 16 dtiles sharing one 256KB Res slice land on
// ONE XCD (4 slices = 1MB <= 4MB L2).
// ---------------------------------------------------------------------------
__global__ void out_kernel(const float2* __restrict__ Res,
                           const float* __restrict__ wor, const float* __restrict__ woi,
                           float* __restrict__ out) {
    int bid = blockIdx.x;
    int xcd = bid & 7;
    int idx = bid >> 3;                   // 0..63
    int bm = xcd * 4 + (idx & 3);         // b*MM+m, 0..31
    int dt = idx >> 2;                    // 0..15
    int n = threadIdx.x;
    int D0 = dt * DTILE;
    int m = bm & 3;

    __shared__ float2 sw[DTILE][KO];      // 8 KB
    for (int i2 = threadIdx.x; i2 < DTILE * KO; i2 += 256) {
        int d = i2 >> 7, k = i2 & 127;
        int wb = (m * DD + D0 + d) * KO + k;
        sw[d][k] = make_float2(wor[wb], woi[wb]);
    }
    __syncthreads();

    const float2* rp = Res + (size_t)(bm * KO) * NN + n;
    float ar[DTILE], ai[DTILE];
#pragma unroll
    for (int d = 0; d < DTILE; ++d) { ar[d] = 0.f; ai[d] = 0.f; }

    for (int k = 0; k < KO; ++k) {
        float2 r = rp[(size_t)k * NN];    // coalesced
#pragma unroll
        for (int d = 0; d < DTILE; ++d) {
            float2 w = sw[d][k];          // broadcast
            ar[d] = fmaf(w.x, r.x, fmaf(-w.y, r.y, ar[d]));
            ai[d] = fmaf(w.x, r.y, fmaf( w.y, r.x, ai[d]));
        }
    }
#pragma unroll
    for (int d = 0; d < DTILE; ++d) {
        size_t ob = (size_t)(bm * DD + D0 + d) * NN + n;
        out[ob] = ar[d];
        out[(size_t)BB * MM * DD * NN + ob] = ai[d];
    }
}

// ---------------------------------------------------------------------------
extern "C" void kernel_launch(void* const* d_in, const int* in_sizes, int n_in,
                              void* d_out, int out_size, void* d_ws, size_t ws_size,
                              hipStream_t stream) {
    (void)in_sizes; (void)n_in; (void)out_size; (void)ws_size;

    const float* x_re   = (const float*)d_in[0];
    const float* x_im   = (const float*)d_in[1];
    const float* emb_re = (const float*)d_in[2];
    const float* emb_im = (const float*)d_in[3];
    const float* enc_re = (const float*)d_in[4];
    const float* enc_im = (const float*)d_in[5];
    const float* out_re = (const float*)d_in[6];
    const float* out_im = (const float*)d_in[7];
    float* out = (float*)d_out;

    // Workspace layout (floats). Total ~155.7 MB.
    float* ws = (float*)d_ws;
    size_t off = 0;
    float2* peIJ = (float2*)(ws + off); off += (size_t)MM * NN * NN * 2;          // 524288
    float2* peT  = (float2*)(ws + off); off += (size_t)MM * NN * NN * 2;          // 524288
    float2* E    = (float2*)(ws + off); off += (size_t)3 * BB * MM * NHH * QDD * NN * 2; // 25165824
    float2* QE   = (float2*)(ws + off); off += (size_t)BB * MM * NHH * NN * 2;    // 131072
    float2* A    = (float2*)(ws + off); off += (size_t)BB * NHH * NN * NN * 2;    // 8388608
    float*  AwT  = (float*)(ws + off);  off += (size_t)BB * NHH * NN * NN;        // 4194304
    float2* Res  = A;  // alias: A is dead after softmax; Res needs 2097152 floats

    pe_kernel<<<MM * NN, 256, 0, stream>>>(peIJ, peT);
    e_kernel<<<3 * BB * MM * NHH, 256, 0, stream>>>(x_re, x_im, emb_re, emb_im, E);
    qe_kernel<<<BB * MM * NHH, 256, 0, stream>>>(E, enc_re, enc_im, QE);
    a_kernel<<<BB * NHH * ATILE, 256, 0, stream>>>(E, QE, peIJ, A);
    softmax_kernel<<<BB * NHH * NN, 256, 0, stream>>>(A, AwT);
    res_kernel<<<BB * MM * NHH * 2, 512, 0, stream>>>(E, AwT, peT, enc_re, enc_im, Res);
    out_kernel<<<BB * MM * (DD / DTILE), 256, 0, stream>>>(Res, out_re, out_im, out);
}